// Round 2
// baseline (649.255 us; speedup 1.0000x reference)
//
#include <hip/hip_runtime.h>

#define NN 100000
#define DD 128
#define NB ((NN + 255) / 256)  // 391 blocks for node-sized scans

// ---------------------------------------------------------------------------
// counts: icnt layout [4][NN]: 0=out_pos(src_pos), 1=in_pos(dst_pos),
//                              2=out_neg(src_neg), 3=in_neg(dst_neg)
// ---------------------------------------------------------------------------
__global__ __launch_bounds__(256) void count_kernel(
    const int* __restrict__ sp, const int* __restrict__ dp,
    const int* __restrict__ sn, const int* __restrict__ dn,
    int* __restrict__ icnt, int E) {
  int i = blockIdx.x * 256 + threadIdx.x;
  if (i < E) {
    atomicAdd(&icnt[sp[i]], 1);
    atomicAdd(&icnt[NN + dp[i]], 1);
    atomicAdd(&icnt[2 * NN + sn[i]], 1);
    atomicAdd(&icnt[3 * NN + dn[i]], 1);
  }
}

// norm[i] = icnt[i]>0 ? rsqrt(icnt[i]) : 0   (== where(deg>0, rsqrt(max(deg,1)), 0))
__global__ __launch_bounds__(256) void norm_kernel(
    const int* __restrict__ icnt, float* __restrict__ norm, int n) {
  int i = blockIdx.x * 256 + threadIdx.x;
  if (i < n) {
    int c = icnt[i];
    norm[i] = (c > 0) ? rsqrtf((float)c) : 0.0f;
  }
}

// ---------------------------------------------------------------------------
// two-level exclusive scan of in-degree counts -> row_start (CSR offsets)
// gridDim.y = 2 selects pos/neg set.
// ---------------------------------------------------------------------------
__global__ __launch_bounds__(256) void scan_p1(
    const int* __restrict__ icnt, int* __restrict__ part) {
  // set 0: icnt+NN (dst_pos counts); set 1: icnt+3*NN (dst_neg counts)
  const int* cnt = icnt + (blockIdx.y == 0 ? NN : 3 * NN);
  __shared__ int sdata[256];
  int i = blockIdx.x * 256 + threadIdx.x;
  sdata[threadIdx.x] = (i < NN) ? cnt[i] : 0;
  __syncthreads();
  for (int off = 128; off > 0; off >>= 1) {
    if (threadIdx.x < off) sdata[threadIdx.x] += sdata[threadIdx.x + off];
    __syncthreads();
  }
  if (threadIdx.x == 0) part[blockIdx.y * NB + blockIdx.x] = sdata[0];
}

__global__ __launch_bounds__(64) void scan_p2(int* __restrict__ part,
                                              int* __restrict__ rs_p,
                                              int* __restrict__ rs_n, int E) {
  int t = threadIdx.x;
  if (t < 2) {
    int* p = part + t * NB;
    int run = 0;
    for (int i = 0; i < NB; ++i) {
      int v = p[i];
      p[i] = run;
      run += v;
    }
    int* rs = t == 0 ? rs_p : rs_n;
    rs[NN] = E;  // total
  }
}

__global__ __launch_bounds__(256) void scan_p3(
    const int* __restrict__ icnt, const int* __restrict__ part,
    int* __restrict__ rs_p, int* __restrict__ rs_n, int* __restrict__ cur) {
  int set = blockIdx.y;
  const int* cnt = icnt + (set == 0 ? NN : 3 * NN);
  int* rs = set == 0 ? rs_p : rs_n;
  int* cu = cur + set * NN;
  __shared__ int sdata[256];
  int t = threadIdx.x;
  int i = blockIdx.x * 256 + t;
  int v = (i < NN) ? cnt[i] : 0;
  sdata[t] = v;
  __syncthreads();
  // Hillis-Steele inclusive scan
  for (int off = 1; off < 256; off <<= 1) {
    int x = (t >= off) ? sdata[t - off] : 0;
    __syncthreads();
    sdata[t] += x;
    __syncthreads();
  }
  if (i < NN) {
    int start = part[set * NB + blockIdx.x] + sdata[t] - v;  // exclusive
    rs[i] = start;
    cu[i] = start;
  }
}

// ---------------------------------------------------------------------------
// bucket fill: edge_src[cursor[dst]++] = src  (both sets in one pass)
// ---------------------------------------------------------------------------
__global__ __launch_bounds__(256) void fill_kernel(
    const int* __restrict__ sp, const int* __restrict__ dp,
    const int* __restrict__ sn, const int* __restrict__ dn,
    int* __restrict__ cur, int* __restrict__ es_p, int* __restrict__ es_n,
    int E) {
  int i = blockIdx.x * 256 + threadIdx.x;
  if (i < E) {
    int p = atomicAdd(&cur[dp[i]], 1);
    es_p[p] = sp[i];
    int q = atomicAdd(&cur[NN + dn[i]], 1);
    es_n[q] = sn[i];
  }
}

// ---------------------------------------------------------------------------
// y = feats @ W   ([N,128] @ [128,128], f32, VALU)
// block = 256 threads, 64 rows/block, W fully staged in LDS (64 KiB).
// ---------------------------------------------------------------------------
__device__ __forceinline__ float f4c(const float4 v, int k) {
  return k == 0 ? v.x : (k == 1 ? v.y : (k == 2 ? v.z : v.w));
}

__global__ __launch_bounds__(256) void gemm128_kernel(
    const float* __restrict__ A, const float* __restrict__ W,
    float* __restrict__ Y, int nrows) {
  __shared__ float Ws[128 * 128];  // 64 KiB, row-major [k][c]
  int t = threadIdx.x;
  {
    const float4* W4 = (const float4*)W;
    float4* Ws4 = (float4*)Ws;
#pragma unroll
    for (int j = 0; j < 16; ++j) {
      int i = t + 256 * j;
      Ws4[i] = W4[i];
    }
  }
  __syncthreads();

  int tx = t & 15, ty = t >> 4;
  int row0 = blockIdx.x * 64;
  const float4* A4 = (const float4*)A;
  const float4* Ws4 = (const float4*)Ws;

  float acc[4][8];
#pragma unroll
  for (int i = 0; i < 4; ++i)
#pragma unroll
    for (int j = 0; j < 8; ++j) acc[i][j] = 0.0f;

  int r[4];
  bool valid[4];
#pragma unroll
  for (int i = 0; i < 4; ++i) {
    r[i] = row0 + ty * 4 + i;
    valid[i] = r[i] < nrows;
  }

  for (int kc = 0; kc < 32; ++kc) {  // 4 k's per iteration
    float4 a4[4];
#pragma unroll
    for (int i = 0; i < 4; ++i) {
      a4[i] = valid[i] ? A4[(size_t)r[i] * 32 + kc]
                       : make_float4(0.f, 0.f, 0.f, 0.f);
    }
#pragma unroll
    for (int kk = 0; kk < 4; ++kk) {
      int k = kc * 4 + kk;
      float4 w0 = Ws4[k * 32 + tx];
      float4 w1 = Ws4[k * 32 + 16 + tx];
      float wv[8] = {w0.x, w0.y, w0.z, w0.w, w1.x, w1.y, w1.z, w1.w};
#pragma unroll
      for (int i = 0; i < 4; ++i) {
        float av = f4c(a4[i], kk);
#pragma unroll
        for (int j = 0; j < 8; ++j) acc[i][j] += av * wv[j];
      }
    }
  }

  float4* Y4 = (float4*)Y;
#pragma unroll
  for (int i = 0; i < 4; ++i) {
    if (valid[i]) {
      float4 o0 = {acc[i][0], acc[i][1], acc[i][2], acc[i][3]};
      float4 o1 = {acc[i][4], acc[i][5], acc[i][6], acc[i][7]};
      Y4[(size_t)r[i] * 32 + tx] = o0;
      Y4[(size_t)r[i] * 32 + 16 + tx] = o1;
    }
  }
}

// ---------------------------------------------------------------------------
// CSR gather + fused epilogue: no atomics, no d_out pre-zeroing.
// 32 lanes per output row; each lane owns one float4 (16B) of the row.
// out[R] = prelu( (sum_{e in row} norm_s[src_e] * y[src_e]) * norm_d + b )
// ---------------------------------------------------------------------------
__global__ __launch_bounds__(256) void gather_finalize_kernel(
    const float4* __restrict__ y4, const int* __restrict__ rs_p,
    const int* __restrict__ rs_n, const int* __restrict__ es_p,
    const int* __restrict__ es_n, const float* __restrict__ norm,
    const float* __restrict__ b, const float* __restrict__ prelu_a,
    float4* __restrict__ out4) {
  int idx = blockIdx.x * 256 + threadIdx.x;
  int lane = idx & 31;
  int R = idx >> 5;  // 0..2*NN-1
  if (R >= 2 * NN) return;
  int set = R >= NN;
  int r = R - set * NN;

  const int* rs = set ? rs_n : rs_p;
  const int* es = set ? es_n : es_p;
  const float* ns = norm + (set ? 2 * NN : 0);   // out-degree norms of src
  const float* ndv = norm + (set ? 3 * NN : NN); // in-degree norms of dst

  int j0 = rs[r], j1 = rs[r + 1];
  float4 acc = make_float4(0.f, 0.f, 0.f, 0.f);
  for (int j = j0; j < j1; ++j) {
    int s = es[j];
    float sc = ns[s];
    float4 v = y4[(size_t)s * 32 + lane];
    acc.x += sc * v.x;
    acc.y += sc * v.y;
    acc.z += sc * v.z;
    acc.w += sc * v.w;
  }
  float nd = ndv[r];
  float a = prelu_a[0];
  float4 bb = ((const float4*)b)[lane];
  float4 h;
  h.x = acc.x * nd + bb.x;
  h.y = acc.y * nd + bb.y;
  h.z = acc.z * nd + bb.z;
  h.w = acc.w * nd + bb.w;
  h.x = h.x > 0.f ? h.x : a * h.x;
  h.y = h.y > 0.f ? h.y : a * h.y;
  h.z = h.z > 0.f ? h.z : a * h.z;
  h.w = h.w > 0.f ? h.w : a * h.w;
  out4[(size_t)R * 32 + lane] = h;
}

// ---------------------------------------------------------------------------
extern "C" void kernel_launch(void* const* d_in, const int* in_sizes, int n_in,
                              void* d_out, int out_size, void* d_ws, size_t ws_size,
                              hipStream_t stream) {
  const float* feats = (const float*)d_in[0];
  const float* W = (const float*)d_in[1];
  const float* b = (const float*)d_in[2];
  const float* pa = (const float*)d_in[3];
  const int* sp = (const int*)d_in[4];
  const int* dp = (const int*)d_in[5];
  const int* sn = (const int*)d_in[6];
  const int* dn = (const int*)d_in[7];
  int E = in_sizes[4];

  // workspace layout (4B units):
  float* y = (float*)d_ws;            // NN*128
  float* norm = y + (size_t)NN * DD;  // 4*NN
  int* icnt = (int*)(norm + 4 * NN);  // 4*NN
  int* rs_p = icnt + 4 * NN;          // NN+1
  int* rs_n = rs_p + NN + 1;          // NN+1
  int* cur = rs_n + NN + 1;           // 2*NN
  int* es_p = cur + 2 * NN;           // E
  int* es_n = es_p + E;               // E
  int* part = es_n + E;               // 2*NB

  hipMemsetAsync(icnt, 0, (size_t)4 * NN * sizeof(int), stream);

  count_kernel<<<(E + 255) / 256, 256, 0, stream>>>(sp, dp, sn, dn, icnt, E);
  norm_kernel<<<(4 * NN + 255) / 256, 256, 0, stream>>>(icnt, norm, 4 * NN);

  dim3 g1(NB, 2);
  scan_p1<<<g1, 256, 0, stream>>>(icnt, part);
  scan_p2<<<1, 64, 0, stream>>>(part, rs_p, rs_n, E);
  scan_p3<<<g1, 256, 0, stream>>>(icnt, part, rs_p, rs_n, cur);

  fill_kernel<<<(E + 255) / 256, 256, 0, stream>>>(sp, dp, sn, dn, cur, es_p,
                                                   es_n, E);

  gemm128_kernel<<<(NN + 63) / 64, 256, 0, stream>>>(feats, W, y, NN);

  gather_finalize_kernel<<<(2 * NN * 32 + 255) / 256, 256, 0, stream>>>(
      (const float4*)y, rs_p, rs_n, es_p, es_n, norm, b, pa, (float4*)d_out);
}

// Round 11
// 573.385 us; speedup vs baseline: 1.1323x; 1.1323x over previous
//
#include <hip/hip_runtime.h>
#include <stdint.h>

#define NN 100000
#define DD 128
#define NB ((NN + 255) / 256)  // 391 blocks for node-sized scans

// MFMA fragment types — per compile-verified gfx950 examples (short-based):
typedef short bf16x8 __attribute__((ext_vector_type(8)));
typedef float f32x4 __attribute__((ext_vector_type(4)));

__device__ __forceinline__ unsigned short f2bf(float f) {
  unsigned int x = __builtin_bit_cast(unsigned int, f);
  unsigned int r = x + 0x7fffu + ((x >> 16) & 1u);  // RNE
  return (unsigned short)(r >> 16);
}
__device__ __forceinline__ float bf2f(unsigned short b) {
  unsigned int x = ((unsigned int)b) << 16;
  return __builtin_bit_cast(float, x);
}

// ---------------------------------------------------------------------------
// counts: icnt layout [4][NN]: 0=out_pos(src_pos), 1=in_pos(dst_pos),
//                              2=out_neg(src_neg), 3=in_neg(dst_neg)
// ---------------------------------------------------------------------------
__global__ __launch_bounds__(256) void count_kernel(
    const int* __restrict__ sp, const int* __restrict__ dp,
    const int* __restrict__ sn, const int* __restrict__ dn,
    int* __restrict__ icnt, int E) {
  int i = blockIdx.x * 256 + threadIdx.x;
  if (i < E) {
    atomicAdd(&icnt[sp[i]], 1);
    atomicAdd(&icnt[NN + dp[i]], 1);
    atomicAdd(&icnt[2 * NN + sn[i]], 1);
    atomicAdd(&icnt[3 * NN + dn[i]], 1);
  }
}

__global__ __launch_bounds__(256) void norm_kernel(
    const int* __restrict__ icnt, float* __restrict__ norm, int n) {
  int i = blockIdx.x * 256 + threadIdx.x;
  if (i < n) {
    int c = icnt[i];
    norm[i] = (c > 0) ? rsqrtf((float)c) : 0.0f;
  }
}

// ---------------------------------------------------------------------------
// two-level exclusive scan of in-degree counts -> row_start (CSR offsets)
// ---------------------------------------------------------------------------
__global__ __launch_bounds__(256) void scan_p1(
    const int* __restrict__ icnt, int* __restrict__ part) {
  const int* cnt = icnt + (blockIdx.y == 0 ? NN : 3 * NN);
  __shared__ int sdata[256];
  int i = blockIdx.x * 256 + threadIdx.x;
  sdata[threadIdx.x] = (i < NN) ? cnt[i] : 0;
  __syncthreads();
  for (int off = 128; off > 0; off >>= 1) {
    if (threadIdx.x < off) sdata[threadIdx.x] += sdata[threadIdx.x + off];
    __syncthreads();
  }
  if (threadIdx.x == 0) part[blockIdx.y * NB + blockIdx.x] = sdata[0];
}

// parallel exclusive scan of the 391 block-partials (x2 sets), one block
__global__ __launch_bounds__(512) void scan_p2(int* __restrict__ part,
                                               int* __restrict__ rs_p,
                                               int* __restrict__ rs_n, int E) {
  __shared__ int s[512];
  int t = threadIdx.x;
#pragma unroll
  for (int set = 0; set < 2; ++set) {
    int v = (t < NB) ? part[set * NB + t] : 0;
    s[t] = v;
    __syncthreads();
    for (int off = 1; off < 512; off <<= 1) {
      int x = (t >= off) ? s[t - off] : 0;
      __syncthreads();
      s[t] += x;
      __syncthreads();
    }
    if (t < NB) part[set * NB + t] = s[t] - v;  // exclusive
    __syncthreads();
  }
  if (t == 0) {
    rs_p[NN] = E;
    rs_n[NN] = E;
  }
}

__global__ __launch_bounds__(256) void scan_p3(
    const int* __restrict__ icnt, const int* __restrict__ part,
    int* __restrict__ rs_p, int* __restrict__ rs_n, int* __restrict__ cur) {
  int set = blockIdx.y;
  const int* cnt = icnt + (set == 0 ? NN : 3 * NN);
  int* rs = set == 0 ? rs_p : rs_n;
  int* cu = cur + set * NN;
  __shared__ int sdata[256];
  int t = threadIdx.x;
  int i = blockIdx.x * 256 + t;
  int v = (i < NN) ? cnt[i] : 0;
  sdata[t] = v;
  __syncthreads();
  for (int off = 1; off < 256; off <<= 1) {
    int x = (t >= off) ? sdata[t - off] : 0;
    __syncthreads();
    sdata[t] += x;
    __syncthreads();
  }
  if (i < NN) {
    int start = part[set * NB + blockIdx.x] + sdata[t] - v;
    rs[i] = start;
    cu[i] = start;
  }
}

// ---------------------------------------------------------------------------
// bucket fill: edge_src[cursor[dst]++] = src  (both sets in one pass)
// nontemporal stores: A/B test vs round-2's 108 MB WRITE_SIZE line-dirtying
// ---------------------------------------------------------------------------
__global__ __launch_bounds__(256) void fill_kernel(
    const int* __restrict__ sp, const int* __restrict__ dp,
    const int* __restrict__ sn, const int* __restrict__ dn,
    int* __restrict__ cur, int* __restrict__ es_p, int* __restrict__ es_n,
    int E) {
  int i = blockIdx.x * 256 + threadIdx.x;
  if (i < E) {
    int p = atomicAdd(&cur[dp[i]], 1);
    __builtin_nontemporal_store(sp[i], es_p + p);
    int q = atomicAdd(&cur[NN + dn[i]], 1);
    __builtin_nontemporal_store(sn[i], es_n + q);
  }
}

// ---------------------------------------------------------------------------
// W fragment prep: swizzle W (f32 [128][128]) into MFMA B-fragment order,
// split into bf16 hi/lo. Layout: Wf[((c*4+t)*64+l)*8+j] =
//   bf16(W[t*32 + (l>>4)*8 + j][c*16 + (l&15)])
// ---------------------------------------------------------------------------
__global__ __launch_bounds__(256) void wprep_kernel(
    const float* __restrict__ W, unsigned short* __restrict__ Wf_hi,
    unsigned short* __restrict__ Wf_lo) {
  int idx = blockIdx.x * 256 + threadIdx.x;  // 0..16383
  int c = idx >> 11;
  int t = (idx >> 9) & 3;
  int l = (idx >> 3) & 63;
  int j = idx & 7;
  int k = t * 32 + ((l >> 4) << 3) + j;
  int n = c * 16 + (l & 15);
  float w = W[k * 128 + n];
  unsigned short hi = f2bf(w);
  float lo = w - bf2f(hi);
  Wf_hi[idx] = hi;
  Wf_lo[idx] = f2bf(lo);
}

// ---------------------------------------------------------------------------
// y = feats @ W via bf16x3 split-precision MFMA (16x16x32).
// Block = 256 threads = 4 waves; each wave owns 16 rows x 128 cols; no LDS.
// A frag: lane l holds A[r0 + (l&15)][t*32 + (l>>4)*8 + j], j=0..7.
// B frag: preswizzled Wf (one 16B load per (c,t)).
// C/D: row = (l>>4)*4 + reg, col = l&15   [verified layout, learn_hip m89/m91]
// ---------------------------------------------------------------------------
__global__ __launch_bounds__(256) void gemm_mfma_kernel(
    const float* __restrict__ A, const unsigned short* __restrict__ Wf_hi,
    const unsigned short* __restrict__ Wf_lo, float* __restrict__ Y,
    int nrows) {
  int wave = threadIdx.x >> 6;
  int lane = threadIdx.x & 63;
  int r0 = blockIdx.x * 64 + wave * 16;
  int arow = r0 + (lane & 15);
  int kg = lane >> 4;

  f32x4 acc[8];
#pragma unroll
  for (int c = 0; c < 8; ++c) acc[c] = (f32x4)(0.0f);

  bool avalid = arow < nrows;
  const float* abase = A + (size_t)arow * 128 + kg * 8;

#pragma unroll
  for (int t = 0; t < 4; ++t) {
    float av[8];
    if (avalid) {
      float4 a0 = ((const float4*)(abase + t * 32))[0];
      float4 a1 = ((const float4*)(abase + t * 32))[1];
      av[0] = a0.x; av[1] = a0.y; av[2] = a0.z; av[3] = a0.w;
      av[4] = a1.x; av[5] = a1.y; av[6] = a1.z; av[7] = a1.w;
    } else {
#pragma unroll
      for (int j = 0; j < 8; ++j) av[j] = 0.0f;
    }
    union { bf16x8 v; unsigned short u[8]; } ah, al;
#pragma unroll
    for (int j = 0; j < 8; ++j) {
      unsigned short h = f2bf(av[j]);
      ah.u[j] = h;
      al.u[j] = f2bf(av[j] - bf2f(h));
    }
#pragma unroll
    for (int c = 0; c < 8; ++c) {
      const bf16x8 bh = *(const bf16x8*)(Wf_hi + (((c * 4 + t) * 64 + lane) << 3));
      const bf16x8 bl = *(const bf16x8*)(Wf_lo + (((c * 4 + t) * 64 + lane) << 3));
      acc[c] = __builtin_amdgcn_mfma_f32_16x16x32_bf16(ah.v, bh, acc[c], 0, 0, 0);
      acc[c] = __builtin_amdgcn_mfma_f32_16x16x32_bf16(al.v, bh, acc[c], 0, 0, 0);
      acc[c] = __builtin_amdgcn_mfma_f32_16x16x32_bf16(ah.v, bl, acc[c], 0, 0, 0);
    }
  }

  // store: per (c,j): lanes kg write row r0+kg*4+j, col c*16+(l&15)
#pragma unroll
  for (int j = 0; j < 4; ++j) {
    int orow = r0 + kg * 4 + j;
    if (orow < nrows) {
      float* yr = Y + (size_t)orow * 128 + (lane & 15);
#pragma unroll
      for (int c = 0; c < 8; ++c) yr[c * 16] = acc[c][j];
    }
  }
}

// ---------------------------------------------------------------------------
// CSR gather + fused epilogue: no atomics, no d_out pre-zeroing.
// ---------------------------------------------------------------------------
__global__ __launch_bounds__(256) void gather_finalize_kernel(
    const float4* __restrict__ y4, const int* __restrict__ rs_p,
    const int* __restrict__ rs_n, const int* __restrict__ es_p,
    const int* __restrict__ es_n, const float* __restrict__ norm,
    const float* __restrict__ b, const float* __restrict__ prelu_a,
    float4* __restrict__ out4) {
  int idx = blockIdx.x * 256 + threadIdx.x;
  int lane = idx & 31;
  int R = idx >> 5;  // 0..2*NN-1
  if (R >= 2 * NN) return;
  int set = R >= NN;
  int r = R - set * NN;

  const int* rs = set ? rs_n : rs_p;
  const int* es = set ? es_n : es_p;
  const float* ns = norm + (set ? 2 * NN : 0);
  const float* ndv = norm + (set ? 3 * NN : NN);

  int j0 = rs[r], j1 = rs[r + 1];
  float4 acc = make_float4(0.f, 0.f, 0.f, 0.f);
  for (int j = j0; j < j1; ++j) {
    int s = es[j];
    float sc = ns[s];
    float4 v = y4[(size_t)s * 32 + lane];
    acc.x += sc * v.x;
    acc.y += sc * v.y;
    acc.z += sc * v.z;
    acc.w += sc * v.w;
  }
  float nd = ndv[r];
  float a = prelu_a[0];
  float4 bb = ((const float4*)b)[lane];
  float4 h;
  h.x = acc.x * nd + bb.x;
  h.y = acc.y * nd + bb.y;
  h.z = acc.z * nd + bb.z;
  h.w = acc.w * nd + bb.w;
  h.x = h.x > 0.f ? h.x : a * h.x;
  h.y = h.y > 0.f ? h.y : a * h.y;
  h.z = h.z > 0.f ? h.z : a * h.z;
  h.w = h.w > 0.f ? h.w : a * h.w;
  out4[(size_t)R * 32 + lane] = h;
}

// ---------------------------------------------------------------------------
extern "C" void kernel_launch(void* const* d_in, const int* in_sizes, int n_in,
                              void* d_out, int out_size, void* d_ws, size_t ws_size,
                              hipStream_t stream) {
  const float* feats = (const float*)d_in[0];
  const float* W = (const float*)d_in[1];
  const float* b = (const float*)d_in[2];
  const float* pa = (const float*)d_in[3];
  const int* sp = (const int*)d_in[4];
  const int* dp = (const int*)d_in[5];
  const int* sn = (const int*)d_in[6];
  const int* dn = (const int*)d_in[7];
  int E = in_sizes[4];

  // workspace layout (4B units):
  float* y = (float*)d_ws;            // NN*128
  float* norm = y + (size_t)NN * DD;  // 4*NN
  int* icnt = (int*)(norm + 4 * NN);  // 4*NN
  int* rs_p = icnt + 4 * NN;          // NN+1
  int* rs_n = rs_p + NN + 1;          // NN+1
  int* cur = rs_n + NN + 1;           // 2*NN
  int* es_p = cur + 2 * NN;           // E
  int* es_n = es_p + E;               // E
  int* part = es_n + E;               // 2*NB
  // W fragments alias `cur` (dead after fill_kernel; wprep runs after fill).
  // 16B-aligned for bf16x8 vector loads; 64KB + 16B <= cur's 800KB.
  unsigned short* Wf_hi =
      (unsigned short*)(((uintptr_t)cur + 15) & ~(uintptr_t)15);  // 16384
  unsigned short* Wf_lo = Wf_hi + 16384;                          // 16384

  hipMemsetAsync(icnt, 0, (size_t)4 * NN * sizeof(int), stream);

  count_kernel<<<(E + 255) / 256, 256, 0, stream>>>(sp, dp, sn, dn, icnt, E);
  norm_kernel<<<(4 * NN + 255) / 256, 256, 0, stream>>>(icnt, norm, 4 * NN);

  dim3 g1(NB, 2);
  scan_p1<<<g1, 256, 0, stream>>>(icnt, part);
  scan_p2<<<1, 512, 0, stream>>>(part, rs_p, rs_n, E);
  scan_p3<<<g1, 256, 0, stream>>>(icnt, part, rs_p, rs_n, cur);

  fill_kernel<<<(E + 255) / 256, 256, 0, stream>>>(sp, dp, sn, dn, cur, es_p,
                                                   es_n, E);

  wprep_kernel<<<64, 256, 0, stream>>>(W, Wf_hi, Wf_lo);
  gemm_mfma_kernel<<<(NN + 63) / 64, 256, 0, stream>>>(feats, Wf_hi, Wf_lo, y,
                                                       NN);

  gather_finalize_kernel<<<(2 * NN * 32 + 255) / 256, 256, 0, stream>>>(
      (const float4*)y, rs_p, rs_n, es_p, es_n, norm, b, pa, (float4*)d_out);
}